// Round 1
// 183.873 us; speedup vs baseline: 1.0805x; 1.0805x over previous
//
#include <hip/hip_runtime.h>
#include <hip/hip_bf16.h>

#define NN 16384
#define DD 256

typedef unsigned short u16;
typedef unsigned int u32;
typedef unsigned char u8;
typedef long i64;
typedef __attribute__((ext_vector_type(4))) float f32x4;
typedef __attribute__((ext_vector_type(4))) int i32x4;
typedef __attribute__((ext_vector_type(8))) int i32x8;

// async global->LDS, 16B per lane; LDS dest = wave-uniform base + lane*16
static __device__ __forceinline__ void gload16(const u8* g, u8* l) {
    __builtin_amdgcn_global_load_lds(
        (const __attribute__((address_space(1))) void*)g,
        (__attribute__((address_space(3))) void*)l,
        16, 0, 0);
}

// ---------- kernel 1: fp8 e4m3 convert, unified XOR-swizzled layout ----------
// Both A8 and B8: [panel][row 0..127][256 B of k], with kb' = kb ^ ((row&7)<<4).
// This is conflict-free for the 16x16x128 MFMA operand reads (2x ds_read_b128,
// 32 B per lane): each 8-lane phase group (fixed q=lane>>4, m&7=0..7) covers all
// 8 16B granules of bits[4:6] -> all 32 banks exactly once.
__global__ void prep_kernel(const float* __restrict__ img, const float* __restrict__ txt,
                            u8* __restrict__ A8, u8* __restrict__ B8,
                            float* __restrict__ zbuf /* s_row..s_col 32768 f */,
                            float* __restrict__ out) {
    int gid = blockIdx.x * 256 + threadIdx.x;          // 0 .. 1048575  (N*D/4)
    float4 va = ((const float4*)img)[gid];
    float4 vb = ((const float4*)txt)[gid];
    const float S = 1.44269504088896f;                  // log2(e) folded into A
    int pa = __builtin_amdgcn_cvt_pk_fp8_f32(va.x * S, va.y * S, 0, false);
    pa     = __builtin_amdgcn_cvt_pk_fp8_f32(va.z * S, va.w * S, pa, true);
    int pb = __builtin_amdgcn_cvt_pk_fp8_f32(vb.x, vb.y, 0, false);
    pb     = __builtin_amdgcn_cvt_pk_fp8_f32(vb.z, vb.w, pb, true);

    const int r  = gid >> 6;            // global row
    const int rl = r & 127;             // row within 128-panel
    const int pn = r >> 7;              // panel index
    const int ko = (gid & 63) << 2;     // k-byte offset 0..255, step 4
    const int kb = ko ^ ((rl & 7) << 4);  // XOR swizzle, flips bits 4-6, keeps 4-align
    *(u32*)(A8 + ((size_t)pn << 15) + (rl << 8) + kb) = (u32)pa;
    *(u32*)(B8 + ((size_t)pn << 15) + (rl << 8) + kb) = (u32)pb;
    if (gid < 32768) zbuf[gid] = 0.0f;
    if (gid == 0) out[0] = 0.0f;
}

// ---------- kernel 2: MX-scaled fp8 GEMM (K=128/instr) + exp2 + row/col sum + diag ----------
// vs previous (138 us, MfmaUtil 40%): switch 16x16x32 fp8 -> mfma_scale 16x16x128
// f8f6f4 with unit E8M0 scales (0x7F = 2^0). Identical products, 2x MFMA-pipe rate
// (4661 TF measured vs 2190), 4x fewer MFMA instrs, 2x fewer LDS reads.
// MFMA floor 66 us -> 33 us. Barrier structure unchanged (one lever per round).
// Operand layout 16x16x128: row/col = lane&15, k = (lane>>4)*32 + e (natural
// extension of verified 16x16x32 mapping; each lane's 32 k-bytes = 1 scale block).
// -144 exp2 bias folded into the k2==0 MFMA C operand (saves 64 v_sub/tile/wave);
// diag therefore stores (logit*log2e - 144).
__global__ __launch_bounds__(256, 2) void gemm_lse_kernel(
        const u8* __restrict__ A8, const u8* __restrict__ B8,
        float* __restrict__ s_row, float* __restrict__ s_col,
        float* __restrict__ diag) {
    __shared__ u8 sA[32768];        // [128 rows][256 B]  (XOR-swizzled)
    __shared__ u8 sB[32768];        // [128 rows][256 B]  (XOR-swizzled)

    const int t = threadIdx.x;
    const int lane = t & 63;
    const int w = t >> 6;
    const int wr = w >> 1, wc = w & 1;
    const int q = lane >> 4, m = lane & 15;
    const int bi = blockIdx.x & 127;            // resident blocks share B phase
    const int jg = blockIdx.x >> 7;
    const int row0 = bi << 7;

    // ---- stage A panel ONCE: linear 32 KB copy, 8 rounds x 256 lanes x 16 B
    #pragma unroll
    for (int R = 0; R < 8; ++R)
        gload16(A8 + ((size_t)bi << 15) + (R << 12) + (w << 10) + ((size_t)lane << 4),
                &sA[(R << 12) + (w << 10)]);

    const f32x4 fzero = {0.f, 0.f, 0.f, 0.f};
    const f32x4 cinit = {-144.f, -144.f, -144.f, -144.f};   // exp2 bias pre-loaded
    f32x4 acc[4][4];
    f32x4 rp[4] = {fzero, fzero, fzero, fzero};   // row partials, whole block

    #pragma unroll 1
    for (int jt = 0; jt < 16; ++jt) {
        const int ct = (jg << 4) + jt;            // column tile index
        const int col0 = ct << 7;
        __syncthreads();   // all waves done computing previous tile from sB
        #pragma unroll
        for (int R = 0; R < 8; ++R)
            gload16(B8 + ((size_t)ct << 15) + (R << 12) + (w << 10) + ((size_t)lane << 4),
                    &sB[(R << 12) + (w << 10)]);
        __syncthreads();   // drains vmcnt -> sB (and sA on jt=0) ready

        // ---- 32 MFMAs per wave (K=128 each), no barriers inside ----
        #pragma unroll
        for (int k2 = 0; k2 < 2; ++k2) {
            i32x8 af[4], bf[4];
            const int ka = ((k2 << 7) | (q << 5)) ^ ((m & 7) << 4);
            #pragma unroll
            for (int rb = 0; rb < 4; ++rb) {
                const int rr = (wr << 6) + (rb << 4) + m;
                const i32x4 alo = *(const i32x4*)(&sA[(rr << 8) + ka]);
                const i32x4 ahi = *(const i32x4*)(&sA[(rr << 8) + (ka ^ 16)]);
                af[rb] = __builtin_shufflevector(alo, ahi, 0, 1, 2, 3, 4, 5, 6, 7);
                const int cr = (wc << 6) + (rb << 4) + m;
                const i32x4 blo = *(const i32x4*)(&sB[(cr << 8) + ka]);
                const i32x4 bhi = *(const i32x4*)(&sB[(cr << 8) + (ka ^ 16)]);
                bf[rb] = __builtin_shufflevector(blo, bhi, 0, 1, 2, 3, 4, 5, 6, 7);
            }
            if (k2 == 0) {
                #pragma unroll
                for (int rb = 0; rb < 4; ++rb)
                    #pragma unroll
                    for (int cb = 0; cb < 4; ++cb)
                        acc[rb][cb] = __builtin_amdgcn_mfma_scale_f32_16x16x128_f8f6f4(
                            af[rb], bf[cb], cinit, 0, 0, 0, 127, 0, 127);
            } else {
                #pragma unroll
                for (int rb = 0; rb < 4; ++rb)
                    #pragma unroll
                    for (int cb = 0; cb < 4; ++cb)
                        acc[rb][cb] = __builtin_amdgcn_mfma_scale_f32_16x16x128_f8f6f4(
                            af[rb], bf[cb], acc[rb][cb], 0, 0, 0, 127, 0, 127);
            }
        }

        // ---- per-tile epilogue (same measured-clean form; acc already biased) ----
        if (bi == ct && wr == wc) {
            #pragma unroll
            for (int rb = 0; rb < 4; ++rb)
                #pragma unroll
                for (int r = 0; r < 4; ++r)
                    if (m == ((q << 2) | r))
                        diag[row0 + (wr << 6) + (rb << 4) + m] = acc[rb][rb][r];
        }
        #pragma unroll
        for (int rb = 0; rb < 4; ++rb)
            #pragma unroll
            for (int cb = 0; cb < 4; ++cb)
                #pragma unroll
                for (int r = 0; r < 4; ++r)
                    acc[rb][cb][r] = __builtin_amdgcn_exp2f(acc[rb][cb][r]);

        #pragma unroll
        for (int rb = 0; rb < 4; ++rb)
            rp[rb] += (acc[rb][0] + acc[rb][1]) + (acc[rb][2] + acc[rb][3]);

        float cpart = 0.0f;
        #pragma unroll
        for (int cb = 0; cb < 4; ++cb) {
            float v = 0.0f;
            #pragma unroll
            for (int rb = 0; rb < 4; ++rb)
                v += (acc[rb][cb][0] + acc[rb][cb][1]) + (acc[rb][cb][2] + acc[rb][cb][3]);
            v += __shfl_xor(v, 16, 64);
            v += __shfl_xor(v, 32, 64);
            if (q == cb) cpart = v;
        }
        atomicAdd(&s_col[col0 + (wc << 6) + (q << 4) + m], cpart);
    }

    // ---- block-end row reduction ----
    float rout = 0.0f;
    #pragma unroll
    for (int rb = 0; rb < 4; ++rb)
        #pragma unroll
        for (int r = 0; r < 4; ++r) {
            float v = rp[rb][r];
            v += __shfl_xor(v, 1, 16);
            v += __shfl_xor(v, 2, 16);
            v += __shfl_xor(v, 4, 16);
            v += __shfl_xor(v, 8, 16);
            if (m == ((rb << 2) | r)) rout = v;
        }
    atomicAdd(&s_row[row0 + (wr << 6) + ((m >> 2) << 4) + (q << 2) + (m & 3)], rout);
}

// ---------- kernel 3: final reduce (64 blocks, 256 rows each) ----------
// diag is biased by -144; the +144 LSE un-bias cancels it exactly:
// p = 0.5*(log2(s_row)+log2(s_col)) + 144 - x_ii,  diag = x_ii - 144.
__global__ void final_kernel(const float* __restrict__ s_row, const float* __restrict__ s_col,
                             const float* __restrict__ diag, float* __restrict__ out) {
    __shared__ double red[256];
    int t = threadIdx.x;
    int i = blockIdx.x * 256 + t;
    double p = 0.5 * (double)(log2f(s_row[i]) + log2f(s_col[i])) - (double)diag[i];
    red[t] = p;
    __syncthreads();
    for (int s = 128; s > 0; s >>= 1) {
        if (t < s) red[t] += red[t + s];
        __syncthreads();
    }
    if (t == 0) atomicAdd(out, (float)(red[0] * 0.6931471805599453 / (double)NN));
}

// ---------- launch ----------
extern "C" void kernel_launch(void* const* d_in, const int* in_sizes, int n_in,
                              void* d_out, int out_size, void* d_ws, size_t ws_size,
                              hipStream_t stream) {
    const float* img = (const float*)d_in[0];
    const float* txt = (const float*)d_in[1];
    char* ws = (char*)d_ws;
    u8*    A8    = (u8*)ws;                                // 4 MB
    u8*    B8    = (u8*)(ws + 4194304);                    // 4 MB
    float* s_row = (float*)(ws + 8388608);                 // 64 KB
    float* s_col = (float*)(ws + 8388608 + 65536);         // 64 KB
    float* diag  = (float*)(ws + 8388608 + 131072);        // 64 KB
    float* out   = (float*)d_out;

    prep_kernel<<<4096, 256, 0, stream>>>(img, txt, A8, B8, s_row, out);
    gemm_lse_kernel<<<1024, 256, 0, stream>>>(A8, B8, s_row, s_col, diag);
    final_kernel<<<64, 256, 0, stream>>>(s_row, s_col, diag, out);
}

// Round 2
// 168.869 us; speedup vs baseline: 1.1766x; 1.0889x over previous
//
#include <hip/hip_runtime.h>
#include <hip/hip_bf16.h>

#define NN 16384
#define DD 256

typedef unsigned short u16;
typedef unsigned int u32;
typedef unsigned char u8;
typedef long i64;
typedef __attribute__((ext_vector_type(4))) float f32x4;
typedef __attribute__((ext_vector_type(8))) int i32x8;

// async global->LDS, 16B per lane; LDS dest = wave-uniform base + lane*16
static __device__ __forceinline__ void gload16(const u8* g, u8* l) {
    __builtin_amdgcn_global_load_lds(
        (const __attribute__((address_space(1))) void*)g,
        (__attribute__((address_space(3))) void*)l,
        16, 0, 0);
}

// ---------- kernel 1: fp8 e4m3 convert, slot-exact XOR layout ----------
// Both A8 and B8: [panel][row 0..127][256 B of k], byte ko stored at
// kb = ko ^ ((row & 15) << 3)   (permutes 8B slots within the row).
// MFMA operand read j (quad q): in-row slot = ((q<<2)|j) ^ m -> bijective over
// the quad's 16 lanes for every fixed (q,j) -> each 16-lane phase of a
// ds_read_b64 covers all 32 banks exactly once. Zero conflicts (R8-style
// b64 phase-bijectivity; b128 can never be phase-bijective: 256 B > 128 B/phase).
__global__ void prep_kernel(const float* __restrict__ img, const float* __restrict__ txt,
                            u8* __restrict__ A8, u8* __restrict__ B8,
                            float* __restrict__ zbuf /* s_row..s_col 32768 f */,
                            float* __restrict__ out) {
    int gid = blockIdx.x * 256 + threadIdx.x;          // 0 .. 1048575  (N*D/4)
    float4 va = ((const float4*)img)[gid];
    float4 vb = ((const float4*)txt)[gid];
    const float S = 1.44269504088896f;                  // log2(e) folded into A
    int pa = __builtin_amdgcn_cvt_pk_fp8_f32(va.x * S, va.y * S, 0, false);
    pa     = __builtin_amdgcn_cvt_pk_fp8_f32(va.z * S, va.w * S, pa, true);
    int pb = __builtin_amdgcn_cvt_pk_fp8_f32(vb.x, vb.y, 0, false);
    pb     = __builtin_amdgcn_cvt_pk_fp8_f32(vb.z, vb.w, pb, true);

    const int r  = gid >> 6;            // global row
    const int rl = r & 127;             // row within 128-panel
    const int pn = r >> 7;              // panel index
    const int ko = (gid & 63) << 2;     // k-byte offset 0..255, step 4
    const int kb = ko ^ ((rl & 15) << 3);   // slot-exact swizzle, keeps 4B align
    *(u32*)(A8 + ((size_t)pn << 15) + (rl << 8) + kb) = (u32)pa;
    *(u32*)(B8 + ((size_t)pn << 15) + (rl << 8) + kb) = (u32)pb;
    if (gid < 32768) zbuf[gid] = 0.0f;
    if (gid == 0) out[0] = 0.0f;
}

// ---------- kernel 2: MX-scaled fp8 GEMM (K=128/instr) + exp2 + row/col sum + diag ----------
// vs R1 (118 us, MfmaUtil 23%, 8.4M bank conflicts):
// (1) b64 slot-exact reads -> conflicts 8.4M -> ~0 (b128 was +4 cyc each).
// (2) A fragments hoisted to registers once (areg[2][4], 64 VGPR) -- identical
//     across all 16 column tiles; halves per-tile LDS reads.
// (3) tile stagger ct = jg<<4 | ((jt+bi)&15): R1 had all 128 same-jg blocks on
//     the SAME column tile per phase -> 256 same-address atomicAdds to s_col
//     (serialized RMW ~ the unaccounted ~7k cyc/tile). Stagger spreads 16x;
//     B working set/XCD = 16 tiles x 32 KB = 512 KB, still L2-resident.
// Barrier structure unchanged (2 barriers/tile, 64 KB LDS, 2 blocks/CU).
__global__ __launch_bounds__(256, 2) void gemm_lse_kernel(
        const u8* __restrict__ A8, const u8* __restrict__ B8,
        float* __restrict__ s_row, float* __restrict__ s_col,
        float* __restrict__ diag) {
    __shared__ u8 sA[32768];        // [128 rows][256 B]  (slot-XOR swizzled)
    __shared__ u8 sB[32768];        // [128 rows][256 B]  (slot-XOR swizzled)

    const int t = threadIdx.x;
    const int lane = t & 63;
    const int w = t >> 6;
    const int wr = w >> 1, wc = w & 1;
    const int q = lane >> 4, m = lane & 15;
    const int bi = blockIdx.x & 127;
    const int jg = blockIdx.x >> 7;
    const int row0 = bi << 7;

    // ---- stage A panel ONCE: linear 32 KB copy, 8 rounds x 256 lanes x 16 B
    #pragma unroll
    for (int R = 0; R < 8; ++R)
        gload16(A8 + ((size_t)bi << 15) + (R << 12) + (w << 10) + ((size_t)lane << 4),
                &sA[(R << 12) + (w << 10)]);
    __syncthreads();    // drain A staging

    // ---- hoist A fragments to registers (one time, 32 x ds_read_b64) ----
    i32x8 areg[2][4];
    #pragma unroll
    for (int k2 = 0; k2 < 2; ++k2)
        #pragma unroll
        for (int rb = 0; rb < 4; ++rb) {
            const int rr = (wr << 6) + (rb << 4) + m;
            union { i32x8 v; i64 d[4]; } ua;
            #pragma unroll
            for (int j = 0; j < 4; ++j)
                ua.d[j] = *(const i64*)(&sA[(rr << 8) + (k2 << 7)
                           + (((q << 5) | (j << 3)) ^ (m << 3))]);
            areg[k2][rb] = ua.v;
        }

    const f32x4 fzero = {0.f, 0.f, 0.f, 0.f};
    const f32x4 cinit = {-144.f, -144.f, -144.f, -144.f};   // exp2 bias pre-loaded
    f32x4 acc[4][4];
    f32x4 rp[4] = {fzero, fzero, fzero, fzero};   // row partials, whole block

    #pragma unroll 1
    for (int jt = 0; jt < 16; ++jt) {
        const int ct = (jg << 4) | ((jt + bi) & 15);   // staggered column tile
        const int col0 = ct << 7;
        __syncthreads();   // all waves done computing previous tile from sB
        #pragma unroll
        for (int R = 0; R < 8; ++R)
            gload16(B8 + ((size_t)ct << 15) + (R << 12) + (w << 10) + ((size_t)lane << 4),
                    &sB[(R << 12) + (w << 10)]);
        __syncthreads();   // drains vmcnt -> sB ready

        // ---- 32 MFMAs per wave (K=128 each), no barriers inside ----
        #pragma unroll
        for (int k2 = 0; k2 < 2; ++k2) {
            i32x8 bf[4];
            #pragma unroll
            for (int cb = 0; cb < 4; ++cb) {
                const int cr = (wc << 6) + (cb << 4) + m;
                union { i32x8 v; i64 d[4]; } ub;
                #pragma unroll
                for (int j = 0; j < 4; ++j)
                    ub.d[j] = *(const i64*)(&sB[(cr << 8) + (k2 << 7)
                               + (((q << 5) | (j << 3)) ^ (m << 3))]);
                bf[cb] = ub.v;
            }
            if (k2 == 0) {
                #pragma unroll
                for (int rb = 0; rb < 4; ++rb)
                    #pragma unroll
                    for (int cb = 0; cb < 4; ++cb)
                        acc[rb][cb] = __builtin_amdgcn_mfma_scale_f32_16x16x128_f8f6f4(
                            areg[0][rb], bf[cb], cinit, 0, 0, 0, 127, 0, 127);
            } else {
                #pragma unroll
                for (int rb = 0; rb < 4; ++rb)
                    #pragma unroll
                    for (int cb = 0; cb < 4; ++cb)
                        acc[rb][cb] = __builtin_amdgcn_mfma_scale_f32_16x16x128_f8f6f4(
                            areg[1][rb], bf[cb], acc[rb][cb], 0, 0, 0, 127, 0, 127);
            }
        }

        // ---- per-tile epilogue (acc already biased by -144) ----
        if (bi == ct && wr == wc) {
            #pragma unroll
            for (int rb = 0; rb < 4; ++rb)
                #pragma unroll
                for (int r = 0; r < 4; ++r)
                    if (m == ((q << 2) | r))
                        diag[row0 + (wr << 6) + (rb << 4) + m] = acc[rb][rb][r];
        }
        #pragma unroll
        for (int rb = 0; rb < 4; ++rb)
            #pragma unroll
            for (int cb = 0; cb < 4; ++cb)
                #pragma unroll
                for (int r = 0; r < 4; ++r)
                    acc[rb][cb][r] = __builtin_amdgcn_exp2f(acc[rb][cb][r]);

        #pragma unroll
        for (int rb = 0; rb < 4; ++rb)
            rp[rb] += (acc[rb][0] + acc[rb][1]) + (acc[rb][2] + acc[rb][3]);

        float cpart = 0.0f;
        #pragma unroll
        for (int cb = 0; cb < 4; ++cb) {
            float v = 0.0f;
            #pragma unroll
            for (int rb = 0; rb < 4; ++rb)
                v += (acc[rb][cb][0] + acc[rb][cb][1]) + (acc[rb][cb][2] + acc[rb][cb][3]);
            v += __shfl_xor(v, 16, 64);
            v += __shfl_xor(v, 32, 64);
            if (q == cb) cpart = v;
        }
        atomicAdd(&s_col[col0 + (wc << 6) + (q << 4) + m], cpart);
    }

    // ---- block-end row reduction ----
    float rout = 0.0f;
    #pragma unroll
    for (int rb = 0; rb < 4; ++rb)
        #pragma unroll
        for (int r = 0; r < 4; ++r) {
            float v = rp[rb][r];
            v += __shfl_xor(v, 1, 16);
            v += __shfl_xor(v, 2, 16);
            v += __shfl_xor(v, 4, 16);
            v += __shfl_xor(v, 8, 16);
            if (m == ((rb << 2) | r)) rout = v;
        }
    atomicAdd(&s_row[row0 + (wr << 6) + ((m >> 2) << 4) + (q << 2) + (m & 3)], rout);
}

// ---------- kernel 3: final reduce (64 blocks, 256 rows each) ----------
// diag is biased by -144; the +144 LSE un-bias cancels it exactly.
__global__ void final_kernel(const float* __restrict__ s_row, const float* __restrict__ s_col,
                             const float* __restrict__ diag, float* __restrict__ out) {
    __shared__ double red[256];
    int t = threadIdx.x;
    int i = blockIdx.x * 256 + t;
    double p = 0.5 * (double)(log2f(s_row[i]) + log2f(s_col[i])) - (double)diag[i];
    red[t] = p;
    __syncthreads();
    for (int s = 128; s > 0; s >>= 1) {
        if (t < s) red[t] += red[t + s];
        __syncthreads();
    }
    if (t == 0) atomicAdd(out, (float)(red[0] * 0.6931471805599453 / (double)NN));
}

// ---------- launch ----------
extern "C" void kernel_launch(void* const* d_in, const int* in_sizes, int n_in,
                              void* d_out, int out_size, void* d_ws, size_t ws_size,
                              hipStream_t stream) {
    const float* img = (const float*)d_in[0];
    const float* txt = (const float*)d_in[1];
    char* ws = (char*)d_ws;
    u8*    A8    = (u8*)ws;                                // 4 MB
    u8*    B8    = (u8*)(ws + 4194304);                    // 4 MB
    float* s_row = (float*)(ws + 8388608);                 // 64 KB
    float* s_col = (float*)(ws + 8388608 + 65536);         // 64 KB
    float* diag  = (float*)(ws + 8388608 + 131072);        // 64 KB
    float* out   = (float*)d_out;

    prep_kernel<<<4096, 256, 0, stream>>>(img, txt, A8, B8, s_row, out);
    gemm_lse_kernel<<<1024, 256, 0, stream>>>(A8, B8, s_row, s_col, diag);
    final_kernel<<<64, 256, 0, stream>>>(s_row, s_col, diag, out);
}

// Round 3
// 161.202 us; speedup vs baseline: 1.2325x; 1.0476x over previous
//
#include <hip/hip_runtime.h>
#include <hip/hip_bf16.h>

#define NN 16384
#define DD 256

typedef unsigned short u16;
typedef unsigned int u32;
typedef unsigned char u8;
typedef long i64;
typedef __attribute__((ext_vector_type(4))) float f32x4;
typedef __attribute__((ext_vector_type(8))) int i32x8;

// async global->LDS, 16B per lane; LDS dest = wave-uniform base + lane*16
static __device__ __forceinline__ void gload16(const u8* g, u8* l) {
    __builtin_amdgcn_global_load_lds(
        (const __attribute__((address_space(1))) void*)g,
        (__attribute__((address_space(3))) void*)l,
        16, 0, 0);
}

// ---------- kernel 1: fp8 e4m3 convert, slot-exact XOR layout ----------
// Both A8 and B8: [panel][row 0..127][256 B of k], byte ko stored at
// kb = ko ^ ((row & 15) << 3)   (permutes 8B slots within the row).
// MFMA operand read j (quad q): in-row slot = ((q<<2)|j) ^ m -> bijective over
// the quad's 16 lanes for every fixed (q,j) -> each 16-lane phase of a
// ds_read_b64 covers all 32 banks exactly once (R2 measured: conflicts 8.4M -> 0).
__global__ void prep_kernel(const float* __restrict__ img, const float* __restrict__ txt,
                            u8* __restrict__ A8, u8* __restrict__ B8,
                            float* __restrict__ zbuf /* s_row..s_col 32768 f */,
                            float* __restrict__ out) {
    int gid = blockIdx.x * 256 + threadIdx.x;          // 0 .. 1048575  (N*D/4)
    float4 va = ((const float4*)img)[gid];
    float4 vb = ((const float4*)txt)[gid];
    const float S = 1.44269504088896f;                  // log2(e) folded into A
    int pa = __builtin_amdgcn_cvt_pk_fp8_f32(va.x * S, va.y * S, 0, false);
    pa     = __builtin_amdgcn_cvt_pk_fp8_f32(va.z * S, va.w * S, pa, true);
    int pb = __builtin_amdgcn_cvt_pk_fp8_f32(vb.x, vb.y, 0, false);
    pb     = __builtin_amdgcn_cvt_pk_fp8_f32(vb.z, vb.w, pb, true);

    const int r  = gid >> 6;            // global row
    const int rl = r & 127;             // row within 128-panel
    const int pn = r >> 7;              // panel index
    const int ko = (gid & 63) << 2;     // k-byte offset 0..255, step 4
    const int kb = ko ^ ((rl & 15) << 3);   // slot-exact swizzle, keeps 4B align
    *(u32*)(A8 + ((size_t)pn << 15) + (rl << 8) + kb) = (u32)pa;
    *(u32*)(B8 + ((size_t)pn << 15) + (rl << 8) + kb) = (u32)pb;
    if (gid < 32768) zbuf[gid] = 0.0f;
    if (gid == 0) out[0] = 0.0f;
}

// ---------- kernel 2: MX-scaled fp8 GEMM + exp2 + row/col sum + diag ----------
// vs R2 (104 us, MfmaUtil 27%, 0 conflicts): PREFETCH DOUBLE-BUFFER (2-phase T3).
// R2 exposed the full stage gap every tile: barrier -> issue loads -> barrier
// (vmcnt0 drain) -> compute  (~5.6k of 7.8k cyc/tile was this gap). Now:
//   issue STAGE(next tile -> buf^1) FIRST, compute current tile from buf,
//   then ONE __syncthreads (its vmcnt drain waits on loads that had the whole
//   ~3k-cyc compute+epilogue to land -> stall hidden).
// LDS stays 64 KB / 2 blocks/CU: the dedicated sA is gone -- A panel is staged
// into buf0, hoisted to regs (areg[2][4]), then buf0 recycled as a B buffer.
// Hazards: prefetch into buf^1 overwrites the buffer READ last iter; the
// last-iter barrier (lgkm drain) ordered those ds_reads first. A-frag reads
// get their own barrier before buf0's first overwrite. 18 barriers vs 32.
__global__ __launch_bounds__(256, 2) void gemm_lse_kernel(
        const u8* __restrict__ A8, const u8* __restrict__ B8,
        float* __restrict__ s_row, float* __restrict__ s_col,
        float* __restrict__ diag) {
    __shared__ u8 sB0[32768];       // [128 rows][256 B]  (slot-XOR swizzled)
    __shared__ u8 sB1[32768];

    const int t = threadIdx.x;
    const int lane = t & 63;
    const int w = t >> 6;
    const int wr = w >> 1, wc = w & 1;
    const int q = lane >> 4, m = lane & 15;
    const int bi = blockIdx.x & 127;
    const int jg = blockIdx.x >> 7;
    const int row0 = bi << 7;

    // ---- prologue: stage A panel -> buf0, first B tile -> buf1 (concurrent)
    #pragma unroll
    for (int R = 0; R < 8; ++R)
        gload16(A8 + ((size_t)bi << 15) + (R << 12) + (w << 10) + ((size_t)lane << 4),
                &sB0[(R << 12) + (w << 10)]);
    const int ct0 = (jg << 4) | (bi & 15);             // staggered first tile
    #pragma unroll
    for (int R = 0; R < 8; ++R)
        gload16(B8 + ((size_t)ct0 << 15) + (R << 12) + (w << 10) + ((size_t)lane << 4),
                &sB1[(R << 12) + (w << 10)]);
    __syncthreads();    // drain both stages

    // ---- hoist A fragments to registers (one time, 32 x ds_read_b64) ----
    i32x8 areg[2][4];
    #pragma unroll
    for (int k2 = 0; k2 < 2; ++k2)
        #pragma unroll
        for (int rb = 0; rb < 4; ++rb) {
            const int rr = (wr << 6) + (rb << 4) + m;
            union { i32x8 v; i64 d[4]; } ua;
            #pragma unroll
            for (int j = 0; j < 4; ++j)
                ua.d[j] = *(const i64*)(&sB0[(rr << 8) + (k2 << 7)
                           + (((q << 5) | (j << 3)) ^ (m << 3))]);
            areg[k2][rb] = ua.v;
        }
    __syncthreads();    // all waves done reading A from buf0 before its overwrite

    const f32x4 fzero = {0.f, 0.f, 0.f, 0.f};
    const f32x4 cinit = {-144.f, -144.f, -144.f, -144.f};   // exp2 bias pre-loaded
    f32x4 acc[4][4];
    f32x4 rp[4] = {fzero, fzero, fzero, fzero};   // row partials, whole block

    #pragma unroll 1
    for (int jt = 0; jt < 16; ++jt) {
        const int ct = (jg << 4) | ((jt + bi) & 15);   // staggered column tile
        const int col0 = ct << 7;
        u8* rd  = (jt & 1) ? sB0 : sB1;                // jt=0 reads buf1
        u8* wr_ = (jt & 1) ? sB1 : sB0;

        // ---- prefetch next tile FIRST (lands during compute below) ----
        if (jt < 15) {
            const int ctn = (jg << 4) | ((jt + 1 + bi) & 15);
            #pragma unroll
            for (int R = 0; R < 8; ++R)
                gload16(B8 + ((size_t)ctn << 15) + (R << 12) + (w << 10) + ((size_t)lane << 4),
                        &wr_[(R << 12) + (w << 10)]);
        }

        // ---- 32 MFMAs per wave (K=128 each), no barriers inside ----
        #pragma unroll
        for (int k2 = 0; k2 < 2; ++k2) {
            i32x8 bf[4];
            #pragma unroll
            for (int cb = 0; cb < 4; ++cb) {
                const int cr = (wc << 6) + (cb << 4) + m;
                union { i32x8 v; i64 d[4]; } ub;
                #pragma unroll
                for (int j = 0; j < 4; ++j)
                    ub.d[j] = *(const i64*)(&rd[(cr << 8) + (k2 << 7)
                               + (((q << 5) | (j << 3)) ^ (m << 3))]);
                bf[cb] = ub.v;
            }
            if (k2 == 0) {
                #pragma unroll
                for (int rb = 0; rb < 4; ++rb)
                    #pragma unroll
                    for (int cb = 0; cb < 4; ++cb)
                        acc[rb][cb] = __builtin_amdgcn_mfma_scale_f32_16x16x128_f8f6f4(
                            areg[0][rb], bf[cb], cinit, 0, 0, 0, 127, 0, 127);
            } else {
                #pragma unroll
                for (int rb = 0; rb < 4; ++rb)
                    #pragma unroll
                    for (int cb = 0; cb < 4; ++cb)
                        acc[rb][cb] = __builtin_amdgcn_mfma_scale_f32_16x16x128_f8f6f4(
                            areg[1][rb], bf[cb], acc[rb][cb], 0, 0, 0, 127, 0, 127);
            }
        }

        // ---- per-tile epilogue (acc already biased by -144) ----
        if (bi == ct && wr == wc) {
            #pragma unroll
            for (int rb = 0; rb < 4; ++rb)
                #pragma unroll
                for (int r = 0; r < 4; ++r)
                    if (m == ((q << 2) | r))
                        diag[row0 + (wr << 6) + (rb << 4) + m] = acc[rb][rb][r];
        }
        #pragma unroll
        for (int rb = 0; rb < 4; ++rb)
            #pragma unroll
            for (int cb = 0; cb < 4; ++cb)
                #pragma unroll
                for (int r = 0; r < 4; ++r)
                    acc[rb][cb][r] = __builtin_amdgcn_exp2f(acc[rb][cb][r]);

        #pragma unroll
        for (int rb = 0; rb < 4; ++rb)
            rp[rb] += (acc[rb][0] + acc[rb][1]) + (acc[rb][2] + acc[rb][3]);

        float cpart = 0.0f;
        #pragma unroll
        for (int cb = 0; cb < 4; ++cb) {
            float v = 0.0f;
            #pragma unroll
            for (int rb = 0; rb < 4; ++rb)
                v += (acc[rb][cb][0] + acc[rb][cb][1]) + (acc[rb][cb][2] + acc[rb][cb][3]);
            v += __shfl_xor(v, 16, 64);
            v += __shfl_xor(v, 32, 64);
            if (q == cb) cpart = v;
        }
        atomicAdd(&s_col[col0 + (wc << 6) + (q << 4) + m], cpart);

        // ---- single barrier per tile: drains prefetch (fully overlapped) ----
        if (jt < 15) __syncthreads();
    }

    // ---- block-end row reduction ----
    float rout = 0.0f;
    #pragma unroll
    for (int rb = 0; rb < 4; ++rb)
        #pragma unroll
        for (int r = 0; r < 4; ++r) {
            float v = rp[rb][r];
            v += __shfl_xor(v, 1, 16);
            v += __shfl_xor(v, 2, 16);
            v += __shfl_xor(v, 4, 16);
            v += __shfl_xor(v, 8, 16);
            if (m == ((rb << 2) | r)) rout = v;
        }
    atomicAdd(&s_row[row0 + (wr << 6) + ((m >> 2) << 4) + (q << 2) + (m & 3)], rout);
}

// ---------- kernel 3: final reduce (64 blocks, 256 rows each) ----------
// diag is biased by -144; the +144 LSE un-bias cancels it exactly.
__global__ void final_kernel(const float* __restrict__ s_row, const float* __restrict__ s_col,
                             const float* __restrict__ diag, float* __restrict__ out) {
    __shared__ double red[256];
    int t = threadIdx.x;
    int i = blockIdx.x * 256 + t;
    double p = 0.5 * (double)(log2f(s_row[i]) + log2f(s_col[i])) - (double)diag[i];
    red[t] = p;
    __syncthreads();
    for (int s = 128; s > 0; s >>= 1) {
        if (t < s) red[t] += red[t + s];
        __syncthreads();
    }
    if (t == 0) atomicAdd(out, (float)(red[0] * 0.6931471805599453 / (double)NN));
}

// ---------- launch ----------
extern "C" void kernel_launch(void* const* d_in, const int* in_sizes, int n_in,
                              void* d_out, int out_size, void* d_ws, size_t ws_size,
                              hipStream_t stream) {
    const float* img = (const float*)d_in[0];
    const float* txt = (const float*)d_in[1];
    char* ws = (char*)d_ws;
    u8*    A8    = (u8*)ws;                                // 4 MB
    u8*    B8    = (u8*)(ws + 4194304);                    // 4 MB
    float* s_row = (float*)(ws + 8388608);                 // 64 KB
    float* s_col = (float*)(ws + 8388608 + 65536);         // 64 KB
    float* diag  = (float*)(ws + 8388608 + 131072);        // 64 KB
    float* out   = (float*)d_out;

    prep_kernel<<<4096, 256, 0, stream>>>(img, txt, A8, B8, s_row, out);
    gemm_lse_kernel<<<1024, 256, 0, stream>>>(A8, B8, s_row, s_col, diag);
    final_kernel<<<64, 256, 0, stream>>>(s_row, s_col, diag, out);
}

// Round 4
// 151.010 us; speedup vs baseline: 1.3157x; 1.0675x over previous
//
#include <hip/hip_runtime.h>
#include <hip/hip_bf16.h>

#define NN 16384
#define DD 256

typedef unsigned short u16;
typedef unsigned int u32;
typedef unsigned char u8;
typedef long i64;
typedef __attribute__((ext_vector_type(4))) float f32x4;
typedef __attribute__((ext_vector_type(4))) int i32x4;
typedef __attribute__((ext_vector_type(8))) int i32x8;

// async global->LDS, 16B per lane; LDS dest = wave-uniform base + lane*16
static __device__ __forceinline__ void gload16(const u8* g, u8* l) {
    __builtin_amdgcn_global_load_lds(
        (const __attribute__((address_space(1))) void*)g,
        (__attribute__((address_space(3))) void*)l,
        16, 0, 0);
}

// ---------- kernel 1: fp8 e4m3 convert ----------
// A8: [panel][row 0..127][256 B], byte ko stored at ko ^ ((row&15)<<3)
//     (slot-exact swizzle; R2 measured 0 LDS conflicts on the b64 hoist reads).
// B8: FRAGMENT-LINEAR layout for direct global->VGPR loads:
//     addr = pn<<15 | k2<<14 | cb8<<11 | j<<10 | q<<8 | m<<4 | u
//     holding fp8 of row (pn*128 + cb8*16 + m), kbyte (k2*128 + q*32 + j*16 + u).
//     A wave's fragment load (fixed ct,k2,cb8,j) is base + lane*16 -> one fully
//     coalesced global_load_dwordx4 (1 KB/instr) per fragment half.
__global__ void prep_kernel(const float* __restrict__ img, const float* __restrict__ txt,
                            u8* __restrict__ A8, u8* __restrict__ B8,
                            float* __restrict__ zbuf /* s_row..s_col 32768 f */,
                            float* __restrict__ out) {
    int gid = blockIdx.x * 256 + threadIdx.x;          // 0 .. 1048575  (N*D/4)
    float4 va = ((const float4*)img)[gid];
    float4 vb = ((const float4*)txt)[gid];
    const float S = 1.44269504088896f;                  // log2(e) folded into A
    int pa = __builtin_amdgcn_cvt_pk_fp8_f32(va.x * S, va.y * S, 0, false);
    pa     = __builtin_amdgcn_cvt_pk_fp8_f32(va.z * S, va.w * S, pa, true);
    int pb = __builtin_amdgcn_cvt_pk_fp8_f32(vb.x, vb.y, 0, false);
    pb     = __builtin_amdgcn_cvt_pk_fp8_f32(vb.z, vb.w, pb, true);

    const int r  = gid >> 6;            // global row
    const int rl = r & 127;             // row within 128-panel
    const int pn = r >> 7;              // panel index
    const int ko = (gid & 63) << 2;     // k-byte offset 0..255, step 4
    // A: LDS-stage swizzled layout (unchanged)
    const int kbA = ko ^ ((rl & 15) << 3);
    *(u32*)(A8 + ((size_t)pn << 15) + (rl << 8) + kbA) = (u32)pa;
    // B: fragment-linear
    const int mm  = rl & 15, cb8 = rl >> 4;
    const int k2  = ko >> 7, koo = ko & 127;
    const int qq  = koo >> 5, jj = (koo >> 4) & 1, u = ko & 15;
    *(u32*)(B8 + ((size_t)pn << 15) + (k2 << 14) + (cb8 << 11) + (jj << 10)
               + (qq << 8) + (mm << 4) + u) = (u32)pb;
    if (gid < 32768) zbuf[gid] = 0.0f;
    if (gid == 0) out[0] = 0.0f;
}

// ---------- kernel 2: MX-scaled fp8 GEMM + exp2 + row/col sum + diag ----------
// vs R3 (99 us, MfmaUtil 29%, 4.19M conflicts): B LDS STAGING ELIMINATED.
// R3 was epilogue-serialized: barrier-locked waves all ran exp2/reduce while the
// matrix pipe idled (~3k of 7.4k cyc/tile), and gload_lds writes collided with
// ds_reads (4.19M conflict-cycles). Now B fragments come straight from L2 via
// coalesced dwordx4 (fragment-linear layout), so the main loop has ZERO barriers
// and zero LDS traffic -> waves free-run, one wave's epilogue overlaps another's
// MFMAs. In-register pipeline: load k2=1 frags under MFMA group 0; prefetch next
// tile's k2=0 frags under MFMA group 1 + epilogue. setprio(1) wraps MFMA (T5 --
// meaningful now that waves occupy different roles at any instant).
// A path unchanged: one 32 KB LDS stage -> areg[2][4] hoist -> LDS idle.
// L2 budget: 16 frag-KB/wave/tile * 4096 wave-tiles * 16 = 1.07 GB, shared
// working set 512 KB/XCD; wr-pairs read identical addresses -> L1 halves L2 load.
__global__ __launch_bounds__(256, 2) void gemm_lse_kernel(
        const u8* __restrict__ A8, const u8* __restrict__ B8,
        float* __restrict__ s_row, float* __restrict__ s_col,
        float* __restrict__ diag) {
    __shared__ u8 sA[32768];        // [128 rows][256 B]  (slot-XOR swizzled)

    const int t = threadIdx.x;
    const int lane = t & 63;
    const int w = t >> 6;
    const int wr = w >> 1, wc = w & 1;
    const int q = lane >> 4, m = lane & 15;
    const int bi = blockIdx.x & 127;
    const int jg = blockIdx.x >> 7;
    const int row0 = bi << 7;

    // ---- stage A panel -> LDS (only LDS use in the kernel)
    #pragma unroll
    for (int R = 0; R < 8; ++R)
        gload16(A8 + ((size_t)bi << 15) + (R << 12) + (w << 10) + ((size_t)lane << 4),
                &sA[(R << 12) + (w << 10)]);
    __syncthreads();    // drain A staging (the only barrier in this kernel)

    // ---- hoist A fragments to registers (one time, 32 x ds_read_b64) ----
    i32x8 areg[2][4];
    #pragma unroll
    for (int k2 = 0; k2 < 2; ++k2)
        #pragma unroll
        for (int rb = 0; rb < 4; ++rb) {
            const int rr = (wr << 6) + (rb << 4) + m;
            union { i32x8 v; i64 d[4]; } ua;
            #pragma unroll
            for (int j = 0; j < 4; ++j)
                ua.d[j] = *(const i64*)(&sA[(rr << 8) + (k2 << 7)
                           + (((q << 5) | (j << 3)) ^ (m << 3))]);
            areg[k2][rb] = ua.v;
        }

    const f32x4 fzero = {0.f, 0.f, 0.f, 0.f};
    const f32x4 cinit = {-144.f, -144.f, -144.f, -144.f};   // exp2 bias pre-loaded
    f32x4 acc[4][4];
    f32x4 rp[4] = {fzero, fzero, fzero, fzero};   // row partials, whole block

    // lane-fixed part of B fragment addresses
    const u8* Bw = B8 + (wc << 13) + ((size_t)lane << 4);

    i32x8 bfA[4], bfB[4];   // k2=0 / k2=1 fragment sets (in-register pipeline)

    // ---- prologue: load tile-0 k2=0 fragments ----
    {
        const int ct0 = (jg << 4) | (bi & 15);
        const u8* p = Bw + ((size_t)ct0 << 15);
        #pragma unroll
        for (int cb = 0; cb < 4; ++cb) {
            i32x4 lo = *(const i32x4*)(p + (cb << 11));
            i32x4 hi = *(const i32x4*)(p + (cb << 11) + 1024);
            bfA[cb] = __builtin_shufflevector(lo, hi, 0, 1, 2, 3, 4, 5, 6, 7);
        }
    }

    #pragma unroll 1
    for (int jt = 0; jt < 16; ++jt) {
        const int ct = (jg << 4) | ((jt + bi) & 15);   // staggered column tile
        const int col0 = ct << 7;
        const u8* p = Bw + ((size_t)ct << 15);

        // ---- load k2=1 fragments (latency hidden under MFMA group 0) ----
        #pragma unroll
        for (int cb = 0; cb < 4; ++cb) {
            i32x4 lo = *(const i32x4*)(p + 16384 + (cb << 11));
            i32x4 hi = *(const i32x4*)(p + 16384 + (cb << 11) + 1024);
            bfB[cb] = __builtin_shufflevector(lo, hi, 0, 1, 2, 3, 4, 5, 6, 7);
        }

        // ---- MFMA group 0 (k2=0), C preloaded with -144 bias ----
        __builtin_amdgcn_s_setprio(1);
        #pragma unroll
        for (int rb = 0; rb < 4; ++rb)
            #pragma unroll
            for (int cb = 0; cb < 4; ++cb)
                acc[rb][cb] = __builtin_amdgcn_mfma_scale_f32_16x16x128_f8f6f4(
                    areg[0][rb], bfA[cb], cinit, 0, 0, 0, 127, 0, 127);
        __builtin_amdgcn_s_setprio(0);

        // ---- prefetch next tile's k2=0 frags (hidden under group 1 + epilogue)
        if (jt < 15) {
            const int ctn = (jg << 4) | ((jt + 1 + bi) & 15);
            const u8* pn2 = Bw + ((size_t)ctn << 15);
            #pragma unroll
            for (int cb = 0; cb < 4; ++cb) {
                i32x4 lo = *(const i32x4*)(pn2 + (cb << 11));
                i32x4 hi = *(const i32x4*)(pn2 + (cb << 11) + 1024);
                bfA[cb] = __builtin_shufflevector(lo, hi, 0, 1, 2, 3, 4, 5, 6, 7);
            }
        }

        // ---- MFMA group 1 (k2=1) ----
        __builtin_amdgcn_s_setprio(1);
        #pragma unroll
        for (int rb = 0; rb < 4; ++rb)
            #pragma unroll
            for (int cb = 0; cb < 4; ++cb)
                acc[rb][cb] = __builtin_amdgcn_mfma_scale_f32_16x16x128_f8f6f4(
                    areg[1][rb], bfB[cb], acc[rb][cb], 0, 0, 0, 127, 0, 127);
        __builtin_amdgcn_s_setprio(0);

        // ---- per-tile epilogue (acc already biased by -144) ----
        if (bi == ct && wr == wc) {
            #pragma unroll
            for (int rb = 0; rb < 4; ++rb)
                #pragma unroll
                for (int r = 0; r < 4; ++r)
                    if (m == ((q << 2) | r))
                        diag[row0 + (wr << 6) + (rb << 4) + m] = acc[rb][rb][r];
        }
        #pragma unroll
        for (int rb = 0; rb < 4; ++rb)
            #pragma unroll
            for (int cb = 0; cb < 4; ++cb)
                #pragma unroll
                for (int r = 0; r < 4; ++r)
                    acc[rb][cb][r] = __builtin_amdgcn_exp2f(acc[rb][cb][r]);

        #pragma unroll
        for (int rb = 0; rb < 4; ++rb)
            rp[rb] += (acc[rb][0] + acc[rb][1]) + (acc[rb][2] + acc[rb][3]);

        float cpart = 0.0f;
        #pragma unroll
        for (int cb = 0; cb < 4; ++cb) {
            float v = 0.0f;
            #pragma unroll
            for (int rb = 0; rb < 4; ++rb)
                v += (acc[rb][cb][0] + acc[rb][cb][1]) + (acc[rb][cb][2] + acc[rb][cb][3]);
            v += __shfl_xor(v, 16, 64);
            v += __shfl_xor(v, 32, 64);
            if (q == cb) cpart = v;
        }
        atomicAdd(&s_col[col0 + (wc << 6) + (q << 4) + m], cpart);
    }

    // ---- block-end row reduction ----
    float rout = 0.0f;
    #pragma unroll
    for (int rb = 0; rb < 4; ++rb)
        #pragma unroll
        for (int r = 0; r < 4; ++r) {
            float v = rp[rb][r];
            v += __shfl_xor(v, 1, 16);
            v += __shfl_xor(v, 2, 16);
            v += __shfl_xor(v, 4, 16);
            v += __shfl_xor(v, 8, 16);
            if (m == ((rb << 2) | r)) rout = v;
        }
    atomicAdd(&s_row[row0 + (wr << 6) + ((m >> 2) << 4) + (q << 2) + (m & 3)], rout);
}

// ---------- kernel 3: final reduce (64 blocks, 256 rows each) ----------
// diag is biased by -144; the +144 LSE un-bias cancels it exactly.
__global__ void final_kernel(const float* __restrict__ s_row, const float* __restrict__ s_col,
                             const float* __restrict__ diag, float* __restrict__ out) {
    __shared__ double red[256];
    int t = threadIdx.x;
    int i = blockIdx.x * 256 + t;
    double p = 0.5 * (double)(log2f(s_row[i]) + log2f(s_col[i])) - (double)diag[i];
    red[t] = p;
    __syncthreads();
    for (int s = 128; s > 0; s >>= 1) {
        if (t < s) red[t] += red[t + s];
        __syncthreads();
    }
    if (t == 0) atomicAdd(out, (float)(red[0] * 0.6931471805599453 / (double)NN));
}

// ---------- launch ----------
extern "C" void kernel_launch(void* const* d_in, const int* in_sizes, int n_in,
                              void* d_out, int out_size, void* d_ws, size_t ws_size,
                              hipStream_t stream) {
    const float* img = (const float*)d_in[0];
    const float* txt = (const float*)d_in[1];
    char* ws = (char*)d_ws;
    u8*    A8    = (u8*)ws;                                // 4 MB
    u8*    B8    = (u8*)(ws + 4194304);                    // 4 MB
    float* s_row = (float*)(ws + 8388608);                 // 64 KB
    float* s_col = (float*)(ws + 8388608 + 65536);         // 64 KB
    float* diag  = (float*)(ws + 8388608 + 131072);        // 64 KB
    float* out   = (float*)d_out;

    prep_kernel<<<4096, 256, 0, stream>>>(img, txt, A8, B8, s_row, out);
    gemm_lse_kernel<<<1024, 256, 0, stream>>>(A8, B8, s_row, s_col, diag);
    final_kernel<<<64, 256, 0, stream>>>(s_row, s_col, diag, out);
}

// Round 6
// 150.249 us; speedup vs baseline: 1.3224x; 1.0051x over previous
//
#include <hip/hip_runtime.h>
#include <hip/hip_bf16.h>

#define NN 16384
#define DD 256

typedef unsigned short u16;
typedef unsigned int u32;
typedef unsigned char u8;
typedef long i64;
typedef __attribute__((ext_vector_type(4))) float f32x4;
typedef __attribute__((ext_vector_type(4))) int i32x4;
typedef __attribute__((ext_vector_type(8))) int i32x8;

// ---------- kernel 1: fp8 e4m3 convert, LDS-transposed, all-coalesced ----------
// A8 and B8 share ONE fragment-linear layout:
//   addr = pn<<15 | k2<<14 | r8<<11 | jj<<10 | qq<<8 | mm<<4 | u
//   holding fp8 of row (pn*128 + r8*16 + mm), kbyte (k2*128 + qq*32 + jj*16 + u).
// prep: block = 16 rows x 256 cols = 1024 float4s (4 per thread -- R5 bug was
// k<16 here: 4x OOB -> LDS overflow -> crash). Coalesced float4 loads -> cvt_pk
// -> LDS (write sA[row*65+lane]: 2 lanes/bank, free; read stride 65 == 1 mod 32,
// 2-way, free) -> barrier -> wave w=(k2,jj), lane l=(qq,mm) stores one 16 B
// granule: ONE contiguous 1 KB store per wave per matrix. R4's prep scattered
// ~1M 4B B-writes over 32 KB regions (~50 us of L2 request-rate limit); now
// reads AND writes are fully coalesced.
__global__ __launch_bounds__(256) void prep_kernel(
        const float* __restrict__ img, const float* __restrict__ txt,
        u8* __restrict__ A8, u8* __restrict__ B8,
        float* __restrict__ zbuf /* s_row..s_col 32768 f */,
        float* __restrict__ out) {
    __shared__ u32 sA[16 * 65 + 8];
    __shared__ u32 sB[16 * 65 + 8];
    const int t = threadIdx.x, bi = blockIdx.x;            // bi = 16-row window
    const float4* ib = (const float4*)img + ((size_t)bi << 10);
    const float4* tb = (const float4*)txt + ((size_t)bi << 10);
    const float S = 1.44269504088896f;                     // log2(e) folded into A
    #pragma unroll
    for (int k = 0; k < 4; ++k) {
        const int idx = (k << 8) + t;                      // 0..1023 float4s
        const int row = idx >> 6, col = idx & 63;          // row 0..15, col 0..63
        float4 va = ib[idx];
        int pa = __builtin_amdgcn_cvt_pk_fp8_f32(va.x * S, va.y * S, 0, false);
        pa     = __builtin_amdgcn_cvt_pk_fp8_f32(va.z * S, va.w * S, pa, true);
        sA[row * 65 + col] = (u32)pa;
        float4 vb = tb[idx];
        int pb = __builtin_amdgcn_cvt_pk_fp8_f32(vb.x, vb.y, 0, false);
        pb     = __builtin_amdgcn_cvt_pk_fp8_f32(vb.z, vb.w, pb, true);
        sB[row * 65 + col] = (u32)pb;
    }
    __syncthreads();
    const int w = t >> 6, l = t & 63;
    const int k2 = w >> 1, jj = w & 1, qq = l >> 4, mm = l & 15;
    const int wb = mm * 65 + (k2 << 5) + (qq << 3) + (jj << 2);
    i32x4 oa = { (int)sA[wb], (int)sA[wb + 1], (int)sA[wb + 2], (int)sA[wb + 3] };
    i32x4 ob = { (int)sB[wb], (int)sB[wb + 1], (int)sB[wb + 2], (int)sB[wb + 3] };
    const size_t dst = ((size_t)(bi >> 3) << 15) + (k2 << 14) + ((size_t)(bi & 7) << 11)
                     + (jj << 10) + (qq << 8) + (mm << 4);
    *(i32x4*)(A8 + dst) = oa;
    *(i32x4*)(B8 + dst) = ob;
    const int gid = (bi << 8) + t;
    if (gid < 32768) zbuf[gid] = 0.0f;
    if (gid == 0) out[0] = 0.0f;
}

// ---------- kernel 2: MX-scaled fp8 GEMM + exp2 + row/col sum + diag ----------
// vs R4 (90.5 us): structure UNCHANGED except the A path -- A8 is now
// fragment-linear, so areg loads are 16 coalesced global dwordx4 (L1 serves the
// wr-pair duplicate). The LDS buffer and the kernel's only __syncthreads are
// gone; the kernel is barrier-free. Main loop verbatim from R4 (measured):
// B frags direct from L2, in-register double pipeline, setprio around MFMA,
// staggered column tiles, -144 bias folded into MFMA C-init.
__global__ __launch_bounds__(256, 2) void gemm_lse_kernel(
        const u8* __restrict__ A8, const u8* __restrict__ B8,
        float* __restrict__ s_row, float* __restrict__ s_col,
        float* __restrict__ diag) {
    const int t = threadIdx.x;
    const int lane = t & 63;
    const int w = t >> 6;
    const int wr = w >> 1, wc = w & 1;
    const int q = lane >> 4, m = lane & 15;
    const int bi = blockIdx.x & 127;
    const int jg = blockIdx.x >> 7;
    const int row0 = bi << 7;

    // ---- A fragments direct from global (fragment-linear, coalesced) ----
    const u8* Aw = A8 + ((size_t)bi << 15) + ((size_t)lane << 4);
    i32x8 areg[2][4];
    #pragma unroll
    for (int k2 = 0; k2 < 2; ++k2)
        #pragma unroll
        for (int rb = 0; rb < 4; ++rb) {
            const u8* p = Aw + (k2 << 14) + (((wr << 2) + rb) << 11);
            i32x4 lo = *(const i32x4*)(p);
            i32x4 hi = *(const i32x4*)(p + 1024);
            areg[k2][rb] = __builtin_shufflevector(lo, hi, 0, 1, 2, 3, 4, 5, 6, 7);
        }

    const f32x4 fzero = {0.f, 0.f, 0.f, 0.f};
    const f32x4 cinit = {-144.f, -144.f, -144.f, -144.f};   // exp2 bias pre-loaded
    f32x4 acc[4][4];
    f32x4 rp[4] = {fzero, fzero, fzero, fzero};   // row partials, whole block

    // lane-fixed part of B fragment addresses
    const u8* Bw = B8 + (wc << 13) + ((size_t)lane << 4);

    i32x8 bfA[4], bfB[4];   // k2=0 / k2=1 fragment sets (in-register pipeline)

    // ---- prologue: load tile-0 k2=0 fragments ----
    {
        const int ct0 = (jg << 4) | (bi & 15);
        const u8* p = Bw + ((size_t)ct0 << 15);
        #pragma unroll
        for (int cb = 0; cb < 4; ++cb) {
            i32x4 lo = *(const i32x4*)(p + (cb << 11));
            i32x4 hi = *(const i32x4*)(p + (cb << 11) + 1024);
            bfA[cb] = __builtin_shufflevector(lo, hi, 0, 1, 2, 3, 4, 5, 6, 7);
        }
    }

    #pragma unroll 1
    for (int jt = 0; jt < 16; ++jt) {
        const int ct = (jg << 4) | ((jt + bi) & 15);   // staggered column tile
        const int col0 = ct << 7;
        const u8* p = Bw + ((size_t)ct << 15);

        // ---- load k2=1 fragments (latency hidden under MFMA group 0) ----
        #pragma unroll
        for (int cb = 0; cb < 4; ++cb) {
            i32x4 lo = *(const i32x4*)(p + 16384 + (cb << 11));
            i32x4 hi = *(const i32x4*)(p + 16384 + (cb << 11) + 1024);
            bfB[cb] = __builtin_shufflevector(lo, hi, 0, 1, 2, 3, 4, 5, 6, 7);
        }

        // ---- MFMA group 0 (k2=0), C preloaded with -144 bias ----
        __builtin_amdgcn_s_setprio(1);
        #pragma unroll
        for (int rb = 0; rb < 4; ++rb)
            #pragma unroll
            for (int cb = 0; cb < 4; ++cb)
                acc[rb][cb] = __builtin_amdgcn_mfma_scale_f32_16x16x128_f8f6f4(
                    areg[0][rb], bfA[cb], cinit, 0, 0, 0, 127, 0, 127);
        __builtin_amdgcn_s_setprio(0);

        // ---- prefetch next tile's k2=0 frags (hidden under group 1 + epilogue)
        if (jt < 15) {
            const int ctn = (jg << 4) | ((jt + 1 + bi) & 15);
            const u8* pn2 = Bw + ((size_t)ctn << 15);
            #pragma unroll
            for (int cb = 0; cb < 4; ++cb) {
                i32x4 lo = *(const i32x4*)(pn2 + (cb << 11));
                i32x4 hi = *(const i32x4*)(pn2 + (cb << 11) + 1024);
                bfA[cb] = __builtin_shufflevector(lo, hi, 0, 1, 2, 3, 4, 5, 6, 7);
            }
        }

        // ---- MFMA group 1 (k2=1) ----
        __builtin_amdgcn_s_setprio(1);
        #pragma unroll
        for (int rb = 0; rb < 4; ++rb)
            #pragma unroll
            for (int cb = 0; cb < 4; ++cb)
                acc[rb][cb] = __builtin_amdgcn_mfma_scale_f32_16x16x128_f8f6f4(
                    areg[1][rb], bfB[cb], acc[rb][cb], 0, 0, 0, 127, 0, 127);
        __builtin_amdgcn_s_setprio(0);

        // ---- per-tile epilogue (acc already biased by -144) ----
        if (bi == ct && wr == wc) {
            #pragma unroll
            for (int rb = 0; rb < 4; ++rb)
                #pragma unroll
                for (int r = 0; r < 4; ++r)
                    if (m == ((q << 2) | r))
                        diag[row0 + (wr << 6) + (rb << 4) + m] = acc[rb][rb][r];
        }
        #pragma unroll
        for (int rb = 0; rb < 4; ++rb)
            #pragma unroll
            for (int cb = 0; cb < 4; ++cb)
                #pragma unroll
                for (int r = 0; r < 4; ++r)
                    acc[rb][cb][r] = __builtin_amdgcn_exp2f(acc[rb][cb][r]);

        #pragma unroll
        for (int rb = 0; rb < 4; ++rb)
            rp[rb] += (acc[rb][0] + acc[rb][1]) + (acc[rb][2] + acc[rb][3]);

        float cpart = 0.0f;
        #pragma unroll
        for (int cb = 0; cb < 4; ++cb) {
            float v = 0.0f;
            #pragma unroll
            for (int rb = 0; rb < 4; ++rb)
                v += (acc[rb][cb][0] + acc[rb][cb][1]) + (acc[rb][cb][2] + acc[rb][cb][3]);
            v += __shfl_xor(v, 16, 64);
            v += __shfl_xor(v, 32, 64);
            if (q == cb) cpart = v;
        }
        atomicAdd(&s_col[col0 + (wc << 6) + (q << 4) + m], cpart);
    }

    // ---- block-end row reduction ----
    float rout = 0.0f;
    #pragma unroll
    for (int rb = 0; rb < 4; ++rb)
        #pragma unroll
        for (int r = 0; r < 4; ++r) {
            float v = rp[rb][r];
            v += __shfl_xor(v, 1, 16);
            v += __shfl_xor(v, 2, 16);
            v += __shfl_xor(v, 4, 16);
            v += __shfl_xor(v, 8, 16);
            if (m == ((rb << 2) | r)) rout = v;
        }
    atomicAdd(&s_row[row0 + (wr << 6) + ((m >> 2) << 4) + (q << 2) + (m & 3)], rout);
}

// ---------- kernel 3: final reduce (64 blocks, 256 rows each) ----------
// diag is biased by -144; the +144 LSE un-bias cancels it exactly.
__global__ void final_kernel(const float* __restrict__ s_row, const float* __restrict__ s_col,
                             const float* __restrict__ diag, float* __restrict__ out) {
    __shared__ double red[256];
    int t = threadIdx.x;
    int i = blockIdx.x * 256 + t;
    double p = 0.5 * (double)(log2f(s_row[i]) + log2f(s_col[i])) - (double)diag[i];
    red[t] = p;
    __syncthreads();
    for (int s = 128; s > 0; s >>= 1) {
        if (t < s) red[t] += red[t + s];
        __syncthreads();
    }
    if (t == 0) atomicAdd(out, (float)(red[0] * 0.6931471805599453 / (double)NN));
}

// ---------- launch ----------
extern "C" void kernel_launch(void* const* d_in, const int* in_sizes, int n_in,
                              void* d_out, int out_size, void* d_ws, size_t ws_size,
                              hipStream_t stream) {
    const float* img = (const float*)d_in[0];
    const float* txt = (const float*)d_in[1];
    char* ws = (char*)d_ws;
    u8*    A8    = (u8*)ws;                                // 4 MB
    u8*    B8    = (u8*)(ws + 4194304);                    // 4 MB
    float* s_row = (float*)(ws + 8388608);                 // 64 KB
    float* s_col = (float*)(ws + 8388608 + 65536);         // 64 KB
    float* diag  = (float*)(ws + 8388608 + 131072);        // 64 KB
    float* out   = (float*)d_out;

    prep_kernel<<<1024, 256, 0, stream>>>(img, txt, A8, B8, s_row, out);
    gemm_lse_kernel<<<1024, 256, 0, stream>>>(A8, B8, s_row, s_col, diag);
    final_kernel<<<64, 256, 0, stream>>>(s_row, s_col, diag, out);
}